// Round 5
// baseline (3862.473 us; speedup 1.0000x reference)
//
#include <hip/hip_runtime.h>

#define BATCH 16
#define NROW  256
#define MCOL  256
#define CDIM  4096
#define INF_F 1e30f
#define CROWS 152   // rows of C cached in LDS (152*256*4 = 155648 B)

// ---------------------------------------------------------------------------
// Fused cost kernel: per-(b,n) softmax stats over C=4096, then 256 cost cols.
// cost[b,n,m] = -softmax(logits[b,n])[lbl[b,m]] + 5 * L1(p[b,n], g[b,m])
// ---------------------------------------------------------------------------
__global__ __launch_bounds__(256)
void cost_fused_kernel(const float* __restrict__ pred_ctrl,
                       const float* __restrict__ logits,
                       const float* __restrict__ gt_ctrl,
                       const int* __restrict__ gt_labels,
                       float* __restrict__ Cout) {
    const int bn = blockIdx.x;                  // b*N + n
    const int b  = bn >> 8;
    const int t  = threadIdx.x;
    const int lane = t & 63, wave = t >> 6;
    const float* rp = logits + (size_t)bn * CDIM;

    __shared__ float part[4];
    __shared__ float smax, ssum;

    float mx = -INF_F;
    for (int c = t; c < CDIM; c += 256) mx = fmaxf(mx, rp[c]);
    for (int off = 32; off; off >>= 1) mx = fmaxf(mx, __shfl_down(mx, off));
    if (lane == 0) part[wave] = mx;
    __syncthreads();
    if (t == 0) smax = fmaxf(fmaxf(part[0], part[1]), fmaxf(part[2], part[3]));
    __syncthreads();
    mx = smax;

    float s = 0.f;
    for (int c = t; c < CDIM; c += 256) s += expf(rp[c] - mx);
    for (int off = 32; off; off >>= 1) s += __shfl_down(s, off);
    __syncthreads();
    if (lane == 0) part[wave] = s;
    __syncthreads();
    if (t == 0) ssum = part[0] + part[1] + part[2] + part[3];
    __syncthreads();

    const float rmax = smax, rsum = ssum;
    const int m = t;

    const float* pp = pred_ctrl + (size_t)bn * 8;
    const float p0 = pp[0], p1 = pp[1], p2 = pp[2], p3 = pp[3];
    const float p4 = pp[4], p5 = pp[5], p6 = pp[6], p7 = pp[7];

    const float* gp = gt_ctrl + ((size_t)b * MCOL + m) * 8;
    const float4 ga = *(const float4*)gp;
    const float4 gb = *(const float4*)(gp + 4);

    const int lbl = gt_labels[b * MCOL + m];
    const float prob = expf(rp[lbl] - rmax) / rsum;

    float cb = fabsf(p0 - ga.x);
    cb += fabsf(p1 - ga.y);
    cb += fabsf(p2 - ga.z);
    cb += fabsf(p3 - ga.w);
    cb += fabsf(p4 - gb.x);
    cb += fabsf(p5 - gb.y);
    cb += fabsf(p6 - gb.z);
    cb += fabsf(p7 - gb.w);

    Cout[(size_t)bn * MCOL + m] = -prob + 5.0f * cb;
}

// ---------------------------------------------------------------------------
// Helpers
// ---------------------------------------------------------------------------
__device__ __forceinline__ unsigned ordkey(float f) {
    unsigned b = __float_as_uint(f);
    return (b & 0x80000000u) ? ~b : (b | 0x80000000u);
}
__device__ __forceinline__ float unordkey(unsigned k) {
    unsigned b = (k & 0x80000000u) ? (k ^ 0x80000000u) : ~k;
    return __uint_as_float(b);
}

template<int CTRL>
__device__ __forceinline__ unsigned dpp_min_step(unsigned x) {
    const unsigned o = (unsigned)__builtin_amdgcn_update_dpp((int)x, (int)x, CTRL, 0xf, 0xf, false);
    return o < x ? o : x;
}
__device__ __forceinline__ unsigned wave_min_u32(unsigned x) {
    x = dpp_min_step<0x111>(x);   // row_shr:1
    x = dpp_min_step<0x112>(x);   // row_shr:2
    x = dpp_min_step<0x114>(x);   // row_shr:4
    x = dpp_min_step<0x118>(x);   // row_shr:8
    x = dpp_min_step<0x142>(x);   // row_bcast:15
    x = dpp_min_step<0x143>(x);   // row_bcast:31
    return (unsigned)__builtin_amdgcn_readlane((int)x, 63);
}

__device__ __forceinline__ float readlane_f(float x, int lane_idx) {
    return __int_as_float(__builtin_amdgcn_readlane(__float_as_int(x), lane_idx));
}
__device__ __forceinline__ float sel4f(float a0, float a1, float a2, float a3, int s) {
    float r = a0;
    r = (s == 1) ? a1 : r;
    r = (s == 2) ? a2 : r;
    r = (s == 3) ? a3 : r;
    return r;
}
__device__ __forceinline__ int sel4i(int a0, int a1, int a2, int a3, int s) {
    int r = a0;
    r = (s == 1) ? a1 : r;
    r = (s == 2) ? a2 : r;
    r = (s == 3) ? a3 : r;
    return r;
}

// ---------------------------------------------------------------------------
// LSA: multi-source (virtual super-source) shortest augmenting path, one wave
// per batch. Lane t owns rows AND cols 4t..4t+3. All state in registers:
//   v0..3 (col duals), u0..3 (row duals), rc0..3 (row4col), cr0..3 (col4row),
//   s0..3 (spc), p0..3 (path), e0..3 (entering dist).
// Init: column reduction (v=colmin) + greedy tight matching.
// Each phase: Dijkstra from ALL free rows at once (virtual source) -> first
// free column popped = shortest augmenting path. Dual update:
//   u_f += D (all free rows), u_i += D - e_i (scanned rows), v_j -= D - spc_j
//   (SC cols). This is the standard virtual-source reduction; maintains dual
//   feasibility + complementary slackness -> same unique optimum as ref.
// ---------------------------------------------------------------------------
__global__ __launch_bounds__(64)
void lsa_kernel(const float* __restrict__ Cmat,
                float* __restrict__ out_row,
                float* __restrict__ out_col) {
    const int b = blockIdx.x;
    const int t = threadIdx.x;
    const int jb = 4 * t;
    const float* C = Cmat + (size_t)b * NROW * MCOL;

    __shared__ float Cc[CROWS][MCOL];     // 155648 B row cache (exact fp32)
    __shared__ int argrow_s[MCOL];
    __shared__ int c4r_s[NROW];
    __shared__ int r4c_s[MCOL];

    // ---------------- column reduction + LDS row staging ----------------
    float m0 = INF_F, m1 = INF_F, m2 = INF_F, m3 = INF_F;
    int   r0 = 0, r1 = 0, r2 = 0, r3 = 0;
    for (int i = 0; i < NROW; i++) {
        const float4 c4 = *(const float4*)(C + (size_t)i * MCOL + jb);
        if (i < CROWS) *(float4*)&Cc[i][jb] = c4;
        if (c4.x < m0) { m0 = c4.x; r0 = i; }
        if (c4.y < m1) { m1 = c4.y; r1 = i; }
        if (c4.z < m2) { m2 = c4.z; r2 = i; }
        if (c4.w < m3) { m3 = c4.w; r3 = i; }
    }
    float v0 = m0, v1 = m1, v2 = m2, v3 = m3;     // v[j], owner lane regs
    float u0 = 0.f, u1 = 0.f, u2 = 0.f, u3 = 0.f; // u[i], owner lane regs

    argrow_s[jb + 0] = r0; argrow_s[jb + 1] = r1;
    argrow_s[jb + 2] = r2; argrow_s[jb + 3] = r3;
    for (int k = 0; k < 4; k++) { c4r_s[jb + k] = -1; r4c_s[jb + k] = -1; }
    __syncthreads();

    if (t == 0) {   // greedy tight matching on column minima
        for (int j = 0; j < MCOL; j++) {
            const int r = argrow_s[j];
            if (c4r_s[r] < 0) { c4r_s[r] = j; r4c_s[j] = r; }
        }
    }
    __syncthreads();

    int4 q;
    q = *(const int4*)&r4c_s[jb];
    int rc0 = q.x, rc1 = q.y, rc2 = q.z, rc3 = q.w;   // row4col mirror
    q = *(const int4*)&c4r_s[jb];
    int cr0 = q.x, cr1 = q.y, cr2 = q.z, cr3 = q.w;   // col4row mirror

    // ---------------- multi-source SAP phases ----------------
    for (int ph = 0; ph < NROW; ph++) {
        unsigned long long mm0 = __ballot(cr0 < 0);
        unsigned long long mm1 = __ballot(cr1 < 0);
        unsigned long long mm2 = __ballot(cr2 < 0);
        unsigned long long mm3 = __ballot(cr3 < 0);
        if (!(mm0 | mm1 | mm2 | mm3)) break;

        float s0 = INF_F, s1 = INF_F, s2 = INF_F, s3 = INF_F;  // spc
        int   p0 = -1,    p1 = -1,    p2 = -1,    p3 = -1;     // path
        float e0 = 0.f, e1 = 0.f, e2 = 0.f, e3 = 0.f;          // entering dist
        int scmask = 0, srmask = 0;

        // source iterator over the free-row bitmasks (wave-uniform SALU)
        auto next_src = [&]() -> int {
            if (mm0) { const int l = __ffsll(mm0) - 1; mm0 &= mm0 - 1; return 4 * l + 0; }
            if (mm1) { const int l = __ffsll(mm1) - 1; mm1 &= mm1 - 1; return 4 * l + 1; }
            if (mm2) { const int l = __ffsll(mm2) - 1; mm2 &= mm2 - 1; return 4 * l + 2; }
            if (mm3) { const int l = __ffsll(mm3) - 1; mm3 &= mm3 - 1; return 4 * l + 3; }
            return -1;
        };
        auto relax0 = [&](int i, const float4& c4) {   // dist-0 relax from source i
            const float ui = readlane_f(sel4f(u0, u1, u2, u3, i & 3), i >> 2);
            float d;
            d = c4.x - ui - v0; if (d < s0) { s0 = d; p0 = i; }
            d = c4.y - ui - v1; if (d < s1) { s1 = d; p1 = i; }
            d = c4.z - ui - v2; if (d < s2) { s2 = d; p2 = i; }
            d = c4.w - ui - v3; if (d < s3) { s3 = d; p3 = i; }
        };

        // ---- init: relax all sources, double-buffered groups of 4 ----
        {
            const float4 z = make_float4(0.f, 0.f, 0.f, 0.f);
            int ia0 = next_src(), ia1 = next_src(), ia2 = next_src(), ia3 = next_src();
            float4 A0 = z, A1 = z, A2 = z, A3 = z;
            if (ia0 >= 0) A0 = *(const float4*)(C + (size_t)ia0 * MCOL + jb);
            if (ia1 >= 0) A1 = *(const float4*)(C + (size_t)ia1 * MCOL + jb);
            if (ia2 >= 0) A2 = *(const float4*)(C + (size_t)ia2 * MCOL + jb);
            if (ia3 >= 0) A3 = *(const float4*)(C + (size_t)ia3 * MCOL + jb);
            while (ia0 >= 0) {
                const int ib0 = next_src(), ib1 = next_src(), ib2 = next_src(), ib3 = next_src();
                float4 B0 = z, B1 = z, B2 = z, B3 = z;
                if (ib0 >= 0) B0 = *(const float4*)(C + (size_t)ib0 * MCOL + jb);
                if (ib1 >= 0) B1 = *(const float4*)(C + (size_t)ib1 * MCOL + jb);
                if (ib2 >= 0) B2 = *(const float4*)(C + (size_t)ib2 * MCOL + jb);
                if (ib3 >= 0) B3 = *(const float4*)(C + (size_t)ib3 * MCOL + jb);
                relax0(ia0, A0);
                if (ia1 >= 0) relax0(ia1, A1);
                if (ia2 >= 0) relax0(ia2, A2);
                if (ia3 >= 0) relax0(ia3, A3);
                ia0 = ib0; A0 = B0; ia1 = ib1; A1 = B1;
                ia2 = ib2; A2 = B2; ia3 = ib3; A3 = B3;
            }
        }

        // ---- Dijkstra pop/expand loop ----
        float minVal = 0.f;
        int sink = -1;
        for (int it = 0; it < MCOL; it++) {
            // argmin over unvisited owned cols, carrying slot + matched row
            unsigned lmin = 0xFFFFFFFFu; int lslot = 0, lrc = -1;
            if (!(scmask & 1)) { const unsigned k = ordkey(s0); if (k < lmin) { lmin = k; lslot = 0; lrc = rc0; } }
            if (!(scmask & 2)) { const unsigned k = ordkey(s1); if (k < lmin) { lmin = k; lslot = 1; lrc = rc1; } }
            if (!(scmask & 4)) { const unsigned k = ordkey(s2); if (k < lmin) { lmin = k; lslot = 2; lrc = rc2; } }
            if (!(scmask & 8)) { const unsigned k = ordkey(s3); if (k < lmin) { lmin = k; lslot = 3; lrc = rc3; } }

            const unsigned g = wave_min_u32(lmin);
            const unsigned long long bal = __ballot(lmin == g);
            const int w = __ffsll(bal) - 1;
            const int pk = __builtin_amdgcn_readlane(((lrc + 1) << 2) | lslot, w);
            const int mj = 4 * w + (pk & 3);
            const int rcx = (pk >> 2) - 1;
            minVal = unordkey(g);

            if (w == t) scmask |= 1 << (pk & 3);
            if (rcx < 0) { sink = mj; break; }

            const int i = rcx;                       // expand matched row i
            if ((i >> 2) == t) {
                const int s = i & 3;
                srmask |= 1 << s;
                e0 = s == 0 ? minVal : e0; e1 = s == 1 ? minVal : e1;
                e2 = s == 2 ? minVal : e2; e3 = s == 3 ? minVal : e3;
            }
            const float ui = readlane_f(sel4f(u0, u1, u2, u3, i & 3), i >> 2);
            float4 c4;
            if (i < CROWS) c4 = *(const float4*)&Cc[i][jb];
            else           c4 = *(const float4*)(C + (size_t)i * MCOL + jb);
            const float base = minVal - ui;
            float d;
            d = base + c4.x - v0; if (!(scmask & 1) && d < s0) { s0 = d; p0 = i; }
            d = base + c4.y - v1; if (!(scmask & 2) && d < s1) { s1 = d; p1 = i; }
            d = base + c4.z - v2; if (!(scmask & 4) && d < s2) { s2 = d; p2 = i; }
            d = base + c4.w - v3; if (!(scmask & 8) && d < s3) { s3 = d; p3 = i; }
        }

        if (sink < 0) break;   // should not happen; avoid corrupting state

        // ---- dual updates (before augment; cr* still phase-start) ----
        if (cr0 < 0) u0 += minVal;                   // free rows: u += D
        if (cr1 < 0) u1 += minVal;
        if (cr2 < 0) u2 += minVal;
        if (cr3 < 0) u3 += minVal;
        if (srmask & 1) u0 += minVal - e0;           // scanned rows
        if (srmask & 2) u1 += minVal - e1;
        if (srmask & 4) u2 += minVal - e2;
        if (srmask & 8) u3 += minVal - e3;
        if (scmask & 1) v0 -= (minVal - s0);         // SC columns
        if (scmask & 2) v1 -= (minVal - s1);
        if (scmask & 4) v2 -= (minVal - s2);
        if (scmask & 8) v3 -= (minVal - s3);

        // ---- augment along predecessor path (registers + readlane) ----
        int j = sink;
        for (int g2 = 0; g2 < NROW; g2++) {
            const int pi = __builtin_amdgcn_readlane(
                sel4i(p0, p1, p2, p3, j & 3), j >> 2);        // path[j]
            if ((j >> 2) == t) {                              // row4col[j] = pi
                const int s = j & 3;
                rc0 = s == 0 ? pi : rc0; rc1 = s == 1 ? pi : rc1;
                rc2 = s == 2 ? pi : rc2; rc3 = s == 3 ? pi : rc3;
            }
            const int jn = __builtin_amdgcn_readlane(
                sel4i(cr0, cr1, cr2, cr3, pi & 3), pi >> 2);  // old col4row[pi]
            if ((pi >> 2) == t) {                             // col4row[pi] = j
                const int s = pi & 3;
                cr0 = s == 0 ? j : cr0; cr1 = s == 1 ? j : cr1;
                cr2 = s == 2 ? j : cr2; cr3 = s == 3 ? j : cr3;
            }
            if (jn < 0) break;                                // pi was a free row
            j = jn;
        }
    }

    out_row[b * NROW + jb + 0] = (float)(jb + 0);
    out_row[b * NROW + jb + 1] = (float)(jb + 1);
    out_row[b * NROW + jb + 2] = (float)(jb + 2);
    out_row[b * NROW + jb + 3] = (float)(jb + 3);
    out_col[b * NROW + jb + 0] = (float)cr0;
    out_col[b * NROW + jb + 1] = (float)cr1;
    out_col[b * NROW + jb + 2] = (float)cr2;
    out_col[b * NROW + jb + 3] = (float)cr3;
}

// ---------------------------------------------------------------------------
extern "C" void kernel_launch(void* const* d_in, const int* in_sizes, int n_in,
                              void* d_out, int out_size, void* d_ws, size_t ws_size,
                              hipStream_t stream) {
    const float* pred_ctrl   = (const float*)d_in[0];
    const float* pred_logits = (const float*)d_in[1];
    const float* gt_ctrl     = (const float*)d_in[2];
    const int*   gt_labels   = (const int*)d_in[3];

    float* out     = (float*)d_out;
    float* out_row = out;
    float* out_col = out + BATCH * NROW;
    float* Cout    = out + 2 * BATCH * NROW;

    cost_fused_kernel<<<BATCH * NROW, 256, 0, stream>>>(pred_ctrl, pred_logits,
                                                        gt_ctrl, gt_labels, Cout);
    lsa_kernel<<<BATCH, 64, 0, stream>>>(Cout, out_row, out_col);
}

// Round 6
// 3355.714 us; speedup vs baseline: 1.1510x; 1.1510x over previous
//
#include <hip/hip_runtime.h>

#define BATCH 16
#define NROW  256
#define MCOL  256
#define CDIM  4096
#define INF_F 1e30f
#define CROWS 150      // rows of C cached in LDS (150*256*4 = 153600 B)
#define MAXSWEEP 40

// ---------------------------------------------------------------------------
// Fused cost kernel: per-(b,n) softmax stats over C=4096, then 256 cost cols.
// ---------------------------------------------------------------------------
__global__ __launch_bounds__(256)
void cost_fused_kernel(const float* __restrict__ pred_ctrl,
                       const float* __restrict__ logits,
                       const float* __restrict__ gt_ctrl,
                       const int* __restrict__ gt_labels,
                       float* __restrict__ Cout) {
    const int bn = blockIdx.x;
    const int b  = bn >> 8;
    const int t  = threadIdx.x;
    const int lane = t & 63, wave = t >> 6;
    const float* rp = logits + (size_t)bn * CDIM;

    __shared__ float part[4];
    __shared__ float smax, ssum;

    float mx = -INF_F;
    for (int c = t; c < CDIM; c += 256) mx = fmaxf(mx, rp[c]);
    for (int off = 32; off; off >>= 1) mx = fmaxf(mx, __shfl_down(mx, off));
    if (lane == 0) part[wave] = mx;
    __syncthreads();
    if (t == 0) smax = fmaxf(fmaxf(part[0], part[1]), fmaxf(part[2], part[3]));
    __syncthreads();
    mx = smax;

    float s = 0.f;
    for (int c = t; c < CDIM; c += 256) s += expf(rp[c] - mx);
    for (int off = 32; off; off >>= 1) s += __shfl_down(s, off);
    __syncthreads();
    if (lane == 0) part[wave] = s;
    __syncthreads();
    if (t == 0) ssum = part[0] + part[1] + part[2] + part[3];
    __syncthreads();

    const float rmax = smax, rsum = ssum;
    const int m = t;

    const float* pp = pred_ctrl + (size_t)bn * 8;
    const float p0 = pp[0], p1 = pp[1], p2 = pp[2], p3 = pp[3];
    const float p4 = pp[4], p5 = pp[5], p6 = pp[6], p7 = pp[7];

    const float* gp = gt_ctrl + ((size_t)b * MCOL + m) * 8;
    const float4 ga = *(const float4*)gp;
    const float4 gb = *(const float4*)(gp + 4);

    const int lbl = gt_labels[b * MCOL + m];
    const float prob = expf(rp[lbl] - rmax) / rsum;

    float cb = fabsf(p0 - ga.x);
    cb += fabsf(p1 - ga.y);
    cb += fabsf(p2 - ga.z);
    cb += fabsf(p3 - ga.w);
    cb += fabsf(p4 - gb.x);
    cb += fabsf(p5 - gb.y);
    cb += fabsf(p6 - gb.z);
    cb += fabsf(p7 - gb.w);

    Cout[(size_t)bn * MCOL + m] = -prob + 5.0f * cb;
}

// ---------------------------------------------------------------------------
// Helpers
// ---------------------------------------------------------------------------
__device__ __forceinline__ unsigned ordkey(float f) {
    unsigned b = __float_as_uint(f);
    return (b & 0x80000000u) ? ~b : (b | 0x80000000u);
}
__device__ __forceinline__ float unordkey(unsigned k) {
    unsigned b = (k & 0x80000000u) ? (k ^ 0x80000000u) : ~k;
    return __uint_as_float(b);
}

template<int CTRL>
__device__ __forceinline__ unsigned dpp_min_step(unsigned x) {
    const unsigned o = (unsigned)__builtin_amdgcn_update_dpp((int)x, (int)x, CTRL, 0xf, 0xf, false);
    return o < x ? o : x;
}
__device__ __forceinline__ unsigned wave_min_u32(unsigned x) {
    x = dpp_min_step<0x111>(x);   // row_shr:1
    x = dpp_min_step<0x112>(x);   // row_shr:2
    x = dpp_min_step<0x114>(x);   // row_shr:4
    x = dpp_min_step<0x118>(x);   // row_shr:8
    x = dpp_min_step<0x142>(x);   // row_bcast:15
    x = dpp_min_step<0x143>(x);   // row_bcast:31
    return (unsigned)__builtin_amdgcn_readlane((int)x, 63);
}

__device__ __forceinline__ float readlane_f(float x, int lane_idx) {
    return __int_as_float(__builtin_amdgcn_readlane(__float_as_int(x), lane_idx));
}
__device__ __forceinline__ float sel4f(float a0, float a1, float a2, float a3, int s) {
    float r = a0;
    r = (s == 1) ? a1 : r;
    r = (s == 2) ? a2 : r;
    r = (s == 3) ? a3 : r;
    return r;
}
__device__ __forceinline__ int sel4i(int a0, int a1, int a2, int a3, int s) {
    int r = a0;
    r = (s == 1) ? a1 : r;
    r = (s == 2) ? a2 : r;
    r = (s == 3) ? a3 : r;
    return r;
}

// ---------------------------------------------------------------------------
// LSA, one wave per batch. Lane t owns rows AND cols 4t..4t+3.
// Stage 1: column reduction (v=colmin) + greedy tight matching.
// Stage 2: parallel Jacobi auction sweeps (eps=0): all free rows scan reduced
//   costs simultaneously, bid gap=mu2-mu1 on argmin col via LDS u64 atomicMax;
//   column takes max-gap bid: u_i=mu2, v_j -= gap, steal. Maintains dual
//   feasibility + tight matched edges (v only decreases; mu2 covers all
//   non-argmin cols) -> exact-optimum-preserving initializer.
// Stage 3: multi-source SAP (virtual super-source) finishes remaining rows
//   exactly (same dual updates as reference; unique optimum).
// ---------------------------------------------------------------------------
__global__ __launch_bounds__(64)
void lsa_kernel(const float* __restrict__ Cmat,
                float* __restrict__ out_row,
                float* __restrict__ out_col) {
    const int b = blockIdx.x;
    const int t = threadIdx.x;
    const int jb = 4 * t;
    const float* C = Cmat + (size_t)b * NROW * MCOL;

    __shared__ float Cc[CROWS][MCOL];               // 153600 B row cache
    __shared__ __align__(16) float v_lds[MCOL];     // col duals (authoritative in sweeps)
    __shared__ unsigned long long bid_s[MCOL];      // bid keys; aliased as argrow in CR
    __shared__ int r4c_s[MCOL];
    __shared__ int c4r_s[NROW];
    int* const argrow_s = (int*)bid_s;

    // ---------------- stage 1: column reduction + LDS staging ----------------
    float m0 = INF_F, m1 = INF_F, m2 = INF_F, m3 = INF_F;
    int   r0 = 0, r1 = 0, r2 = 0, r3 = 0;
    for (int i = 0; i < NROW; i++) {
        const float4 c4 = *(const float4*)(C + (size_t)i * MCOL + jb);
        if (i < CROWS) *(float4*)&Cc[i][jb] = c4;
        if (c4.x < m0) { m0 = c4.x; r0 = i; }
        if (c4.y < m1) { m1 = c4.y; r1 = i; }
        if (c4.z < m2) { m2 = c4.z; r2 = i; }
        if (c4.w < m3) { m3 = c4.w; r3 = i; }
    }
    float u0 = 0.f, u1 = 0.f, u2 = 0.f, u3 = 0.f;   // u[i], owner lane regs

    v_lds[jb + 0] = m0; v_lds[jb + 1] = m1;
    v_lds[jb + 2] = m2; v_lds[jb + 3] = m3;
    argrow_s[jb + 0] = r0; argrow_s[jb + 1] = r1;
    argrow_s[jb + 2] = r2; argrow_s[jb + 3] = r3;
    for (int k = 0; k < 4; k++) { c4r_s[jb + k] = -1; r4c_s[jb + k] = -1; }
    __syncthreads();

    if (t == 0) {   // greedy tight matching on column minima
        for (int j = 0; j < MCOL; j++) {
            const int r = argrow_s[j];
            if (c4r_s[r] < 0) { c4r_s[r] = j; r4c_s[j] = r; }
        }
    }
    __syncthreads();

    // ---------------- stage 2: parallel auction sweeps ----------------
    for (int sweep = 0; sweep < MAXSWEEP; sweep++) {
        const int4 myc = *(const int4*)&c4r_s[jb];   // my rows' match state
        const unsigned long long f0 = __ballot(myc.x < 0);
        const unsigned long long f1 = __ballot(myc.y < 0);
        const unsigned long long f2 = __ballot(myc.z < 0);
        const unsigned long long f3 = __ballot(myc.w < 0);
        if (!(f0 | f1 | f2 | f3)) break;

        bid_s[jb + 0] = 0; bid_s[jb + 1] = 0;
        bid_s[jb + 2] = 0; bid_s[jb + 3] = 0;
        __syncthreads();

        const bool fr[4] = { myc.x < 0, myc.y < 0, myc.z < 0, myc.w < 0 };
        int bj[4]; float gap[4], mu2v[4]; unsigned long long key[4];

        #pragma unroll
        for (int s = 0; s < 4; s++) {
            bj[s] = -1; gap[s] = 0.f; mu2v[s] = 0.f; key[s] = 0;
            if (!fr[s]) continue;
            const int i = jb + s;
            unsigned bk1 = 0xFFFFFFFFu, bk2 = 0xFFFFFFFFu; int bjj = 0;
            if (i < CROWS) {
                for (int j = 0; j < MCOL; j += 4) {
                    const float4 vv = *(const float4*)&v_lds[j];
                    const float4 cc = *(const float4*)&Cc[i][j];
                    unsigned k;
                    k = ordkey(cc.x - vv.x); if (k < bk1) { bk2 = bk1; bk1 = k; bjj = j + 0; } else if (k < bk2) bk2 = k;
                    k = ordkey(cc.y - vv.y); if (k < bk1) { bk2 = bk1; bk1 = k; bjj = j + 1; } else if (k < bk2) bk2 = k;
                    k = ordkey(cc.z - vv.z); if (k < bk1) { bk2 = bk1; bk1 = k; bjj = j + 2; } else if (k < bk2) bk2 = k;
                    k = ordkey(cc.w - vv.w); if (k < bk1) { bk2 = bk1; bk1 = k; bjj = j + 3; } else if (k < bk2) bk2 = k;
                }
            } else {
                const float* rowp = C + (size_t)i * MCOL;
                for (int j = 0; j < MCOL; j += 4) {
                    const float4 vv = *(const float4*)&v_lds[j];
                    const float4 cc = *(const float4*)(rowp + j);
                    unsigned k;
                    k = ordkey(cc.x - vv.x); if (k < bk1) { bk2 = bk1; bk1 = k; bjj = j + 0; } else if (k < bk2) bk2 = k;
                    k = ordkey(cc.y - vv.y); if (k < bk1) { bk2 = bk1; bk1 = k; bjj = j + 1; } else if (k < bk2) bk2 = k;
                    k = ordkey(cc.z - vv.z); if (k < bk1) { bk2 = bk1; bk1 = k; bjj = j + 2; } else if (k < bk2) bk2 = k;
                    k = ordkey(cc.w - vv.w); if (k < bk1) { bk2 = bk1; bk1 = k; bjj = j + 3; } else if (k < bk2) bk2 = k;
                }
            }
            const float mu1 = unordkey(bk1), mu2 = unordkey(bk2);
            gap[s] = mu2 - mu1; mu2v[s] = mu2; bj[s] = bjj;
            key[s] = ((unsigned long long)ordkey(gap[s]) << 32) | (unsigned)i;
            atomicMax(&bid_s[bjj], key[s]);
        }
        __syncthreads();

        int kold[4];
        #pragma unroll
        for (int s = 0; s < 4; s++) {
            kold[s] = -2;   // -2 = not a winner
            if (bj[s] >= 0 && bid_s[bj[s]] == key[s]) kold[s] = r4c_s[bj[s]];
        }
        __syncthreads();

        #pragma unroll
        for (int s = 0; s < 4; s++) {
            if (kold[s] >= -1) {
                const int i = jb + s, j1 = bj[s];
                r4c_s[j1] = i;
                c4r_s[i] = j1;
                if (kold[s] >= 0) c4r_s[kold[s]] = -1;
                v_lds[j1] -= gap[s];
                if (s == 0) u0 = mu2v[0];
                else if (s == 1) u1 = mu2v[1];
                else if (s == 2) u2 = mu2v[2];
                else u3 = mu2v[3];
            }
        }
        __syncthreads();
    }

    // refresh register mirrors
    int4 q;
    q = *(const int4*)&r4c_s[jb];
    int rc0 = q.x, rc1 = q.y, rc2 = q.z, rc3 = q.w;
    q = *(const int4*)&c4r_s[jb];
    int cr0 = q.x, cr1 = q.y, cr2 = q.z, cr3 = q.w;
    const float4 vq = *(const float4*)&v_lds[jb];
    float v0 = vq.x, v1 = vq.y, v2 = vq.z, v3 = vq.w;

    // ---------------- stage 3: multi-source SAP phases (exact) ----------------
    for (int ph = 0; ph < NROW; ph++) {
        unsigned long long mm0 = __ballot(cr0 < 0);
        unsigned long long mm1 = __ballot(cr1 < 0);
        unsigned long long mm2 = __ballot(cr2 < 0);
        unsigned long long mm3 = __ballot(cr3 < 0);
        if (!(mm0 | mm1 | mm2 | mm3)) break;

        float s0 = INF_F, s1 = INF_F, s2 = INF_F, s3 = INF_F;  // spc
        int   p0 = -1,    p1 = -1,    p2 = -1,    p3 = -1;     // path
        float e0 = 0.f, e1 = 0.f, e2 = 0.f, e3 = 0.f;          // entering dist
        int scmask = 0, srmask = 0;

        auto next_src = [&]() -> int {
            if (mm0) { const int l = __ffsll(mm0) - 1; mm0 &= mm0 - 1; return 4 * l + 0; }
            if (mm1) { const int l = __ffsll(mm1) - 1; mm1 &= mm1 - 1; return 4 * l + 1; }
            if (mm2) { const int l = __ffsll(mm2) - 1; mm2 &= mm2 - 1; return 4 * l + 2; }
            if (mm3) { const int l = __ffsll(mm3) - 1; mm3 &= mm3 - 1; return 4 * l + 3; }
            return -1;
        };
        auto relax0 = [&](int i, const float4& c4) {
            const float ui = readlane_f(sel4f(u0, u1, u2, u3, i & 3), i >> 2);
            float d;
            d = c4.x - ui - v0; if (d < s0) { s0 = d; p0 = i; }
            d = c4.y - ui - v1; if (d < s1) { s1 = d; p1 = i; }
            d = c4.z - ui - v2; if (d < s2) { s2 = d; p2 = i; }
            d = c4.w - ui - v3; if (d < s3) { s3 = d; p3 = i; }
        };

        {   // relax all sources, double-buffered groups of 4
            const float4 z = make_float4(0.f, 0.f, 0.f, 0.f);
            int ia0 = next_src(), ia1 = next_src(), ia2 = next_src(), ia3 = next_src();
            float4 A0 = z, A1 = z, A2 = z, A3 = z;
            if (ia0 >= 0) A0 = *(const float4*)(C + (size_t)ia0 * MCOL + jb);
            if (ia1 >= 0) A1 = *(const float4*)(C + (size_t)ia1 * MCOL + jb);
            if (ia2 >= 0) A2 = *(const float4*)(C + (size_t)ia2 * MCOL + jb);
            if (ia3 >= 0) A3 = *(const float4*)(C + (size_t)ia3 * MCOL + jb);
            while (ia0 >= 0) {
                const int ib0 = next_src(), ib1 = next_src(), ib2 = next_src(), ib3 = next_src();
                float4 B0 = z, B1 = z, B2 = z, B3 = z;
                if (ib0 >= 0) B0 = *(const float4*)(C + (size_t)ib0 * MCOL + jb);
                if (ib1 >= 0) B1 = *(const float4*)(C + (size_t)ib1 * MCOL + jb);
                if (ib2 >= 0) B2 = *(const float4*)(C + (size_t)ib2 * MCOL + jb);
                if (ib3 >= 0) B3 = *(const float4*)(C + (size_t)ib3 * MCOL + jb);
                relax0(ia0, A0);
                if (ia1 >= 0) relax0(ia1, A1);
                if (ia2 >= 0) relax0(ia2, A2);
                if (ia3 >= 0) relax0(ia3, A3);
                ia0 = ib0; A0 = B0; ia1 = ib1; A1 = B1;
                ia2 = ib2; A2 = B2; ia3 = ib3; A3 = B3;
            }
        }

        float minVal = 0.f;
        int sink = -1;
        for (int it = 0; it < MCOL; it++) {
            unsigned lmin = 0xFFFFFFFFu; int lslot = 0, lrc = -1;
            if (!(scmask & 1)) { const unsigned k = ordkey(s0); if (k < lmin) { lmin = k; lslot = 0; lrc = rc0; } }
            if (!(scmask & 2)) { const unsigned k = ordkey(s1); if (k < lmin) { lmin = k; lslot = 1; lrc = rc1; } }
            if (!(scmask & 4)) { const unsigned k = ordkey(s2); if (k < lmin) { lmin = k; lslot = 2; lrc = rc2; } }
            if (!(scmask & 8)) { const unsigned k = ordkey(s3); if (k < lmin) { lmin = k; lslot = 3; lrc = rc3; } }

            const unsigned g = wave_min_u32(lmin);
            const unsigned long long bal = __ballot(lmin == g);
            const int w = __ffsll(bal) - 1;
            const int pk = __builtin_amdgcn_readlane(((lrc + 1) << 2) | lslot, w);
            const int mj = 4 * w + (pk & 3);
            const int rcx = (pk >> 2) - 1;
            minVal = unordkey(g);

            if (w == t) scmask |= 1 << (pk & 3);
            if (rcx < 0) { sink = mj; break; }

            const int i = rcx;
            if ((i >> 2) == t) {
                const int s = i & 3;
                srmask |= 1 << s;
                e0 = s == 0 ? minVal : e0; e1 = s == 1 ? minVal : e1;
                e2 = s == 2 ? minVal : e2; e3 = s == 3 ? minVal : e3;
            }
            const float ui = readlane_f(sel4f(u0, u1, u2, u3, i & 3), i >> 2);
            float4 c4;
            if (i < CROWS) c4 = *(const float4*)&Cc[i][jb];
            else           c4 = *(const float4*)(C + (size_t)i * MCOL + jb);
            const float base = minVal - ui;
            float d;
            d = base + c4.x - v0; if (!(scmask & 1) && d < s0) { s0 = d; p0 = i; }
            d = base + c4.y - v1; if (!(scmask & 2) && d < s1) { s1 = d; p1 = i; }
            d = base + c4.z - v2; if (!(scmask & 4) && d < s2) { s2 = d; p2 = i; }
            d = base + c4.w - v3; if (!(scmask & 8) && d < s3) { s3 = d; p3 = i; }
        }

        if (sink < 0) break;

        if (cr0 < 0) u0 += minVal;
        if (cr1 < 0) u1 += minVal;
        if (cr2 < 0) u2 += minVal;
        if (cr3 < 0) u3 += minVal;
        if (srmask & 1) u0 += minVal - e0;
        if (srmask & 2) u1 += minVal - e1;
        if (srmask & 4) u2 += minVal - e2;
        if (srmask & 8) u3 += minVal - e3;
        if (scmask & 1) v0 -= (minVal - s0);
        if (scmask & 2) v1 -= (minVal - s1);
        if (scmask & 4) v2 -= (minVal - s2);
        if (scmask & 8) v3 -= (minVal - s3);

        int j = sink;
        for (int g2 = 0; g2 < NROW; g2++) {
            const int pi = __builtin_amdgcn_readlane(
                sel4i(p0, p1, p2, p3, j & 3), j >> 2);        // path[j]
            if ((j >> 2) == t) {
                const int s = j & 3;
                rc0 = s == 0 ? pi : rc0; rc1 = s == 1 ? pi : rc1;
                rc2 = s == 2 ? pi : rc2; rc3 = s == 3 ? pi : rc3;
            }
            const int jn = __builtin_amdgcn_readlane(
                sel4i(cr0, cr1, cr2, cr3, pi & 3), pi >> 2);  // old col4row[pi]
            if ((pi >> 2) == t) {
                const int s = pi & 3;
                cr0 = s == 0 ? j : cr0; cr1 = s == 1 ? j : cr1;
                cr2 = s == 2 ? j : cr2; cr3 = s == 3 ? j : cr3;
            }
            if (jn < 0) break;
            j = jn;
        }
    }

    out_row[b * NROW + jb + 0] = (float)(jb + 0);
    out_row[b * NROW + jb + 1] = (float)(jb + 1);
    out_row[b * NROW + jb + 2] = (float)(jb + 2);
    out_row[b * NROW + jb + 3] = (float)(jb + 3);
    out_col[b * NROW + jb + 0] = (float)cr0;
    out_col[b * NROW + jb + 1] = (float)cr1;
    out_col[b * NROW + jb + 2] = (float)cr2;
    out_col[b * NROW + jb + 3] = (float)cr3;
}

// ---------------------------------------------------------------------------
extern "C" void kernel_launch(void* const* d_in, const int* in_sizes, int n_in,
                              void* d_out, int out_size, void* d_ws, size_t ws_size,
                              hipStream_t stream) {
    const float* pred_ctrl   = (const float*)d_in[0];
    const float* pred_logits = (const float*)d_in[1];
    const float* gt_ctrl     = (const float*)d_in[2];
    const int*   gt_labels   = (const int*)d_in[3];

    float* out     = (float*)d_out;
    float* out_row = out;
    float* out_col = out + BATCH * NROW;
    float* Cout    = out + 2 * BATCH * NROW;

    cost_fused_kernel<<<BATCH * NROW, 256, 0, stream>>>(pred_ctrl, pred_logits,
                                                        gt_ctrl, gt_labels, Cout);
    lsa_kernel<<<BATCH, 64, 0, stream>>>(Cout, out_row, out_col);
}

// Round 7
// 1784.311 us; speedup vs baseline: 2.1647x; 1.8807x over previous
//
#include <hip/hip_runtime.h>

#define BATCH 16
#define NROW  256
#define MCOL  256
#define CDIM  4096
#define INF_F 1e30f
#define CROWS 150      // rows of C cached in LDS (150*256*4 = 153600 B)
#define MAXSWEEP 32
#define FREETHRESH 6

// ---------------------------------------------------------------------------
// Fused cost kernel: per-(b,n) softmax stats over C=4096, then 256 cost cols.
// ---------------------------------------------------------------------------
__global__ __launch_bounds__(256)
void cost_fused_kernel(const float* __restrict__ pred_ctrl,
                       const float* __restrict__ logits,
                       const float* __restrict__ gt_ctrl,
                       const int* __restrict__ gt_labels,
                       float* __restrict__ Cout) {
    const int bn = blockIdx.x;
    const int b  = bn >> 8;
    const int t  = threadIdx.x;
    const int lane = t & 63, wave = t >> 6;
    const float* rp = logits + (size_t)bn * CDIM;

    __shared__ float part[4];
    __shared__ float smax, ssum;

    float mx = -INF_F;
    for (int c = t; c < CDIM; c += 256) mx = fmaxf(mx, rp[c]);
    for (int off = 32; off; off >>= 1) mx = fmaxf(mx, __shfl_down(mx, off));
    if (lane == 0) part[wave] = mx;
    __syncthreads();
    if (t == 0) smax = fmaxf(fmaxf(part[0], part[1]), fmaxf(part[2], part[3]));
    __syncthreads();
    mx = smax;

    float s = 0.f;
    for (int c = t; c < CDIM; c += 256) s += expf(rp[c] - mx);
    for (int off = 32; off; off >>= 1) s += __shfl_down(s, off);
    __syncthreads();
    if (lane == 0) part[wave] = s;
    __syncthreads();
    if (t == 0) ssum = part[0] + part[1] + part[2] + part[3];
    __syncthreads();

    const float rmax = smax, rsum = ssum;
    const int m = t;

    const float* pp = pred_ctrl + (size_t)bn * 8;
    const float p0 = pp[0], p1 = pp[1], p2 = pp[2], p3 = pp[3];
    const float p4 = pp[4], p5 = pp[5], p6 = pp[6], p7 = pp[7];

    const float* gp = gt_ctrl + ((size_t)b * MCOL + m) * 8;
    const float4 ga = *(const float4*)gp;
    const float4 gb = *(const float4*)(gp + 4);

    const int lbl = gt_labels[b * MCOL + m];
    const float prob = expf(rp[lbl] - rmax) / rsum;

    float cb = fabsf(p0 - ga.x);
    cb += fabsf(p1 - ga.y);
    cb += fabsf(p2 - ga.z);
    cb += fabsf(p3 - ga.w);
    cb += fabsf(p4 - gb.x);
    cb += fabsf(p5 - gb.y);
    cb += fabsf(p6 - gb.z);
    cb += fabsf(p7 - gb.w);

    Cout[(size_t)bn * MCOL + m] = -prob + 5.0f * cb;
}

// ---------------------------------------------------------------------------
// Helpers
// ---------------------------------------------------------------------------
__device__ __forceinline__ unsigned ordkey(float f) {
    unsigned b = __float_as_uint(f);
    return (b & 0x80000000u) ? ~b : (b | 0x80000000u);
}
__device__ __forceinline__ float unordkey(unsigned k) {
    unsigned b = (k & 0x80000000u) ? (k ^ 0x80000000u) : ~k;
    return __uint_as_float(b);
}

template<int CTRL>
__device__ __forceinline__ unsigned dpp_min_step(unsigned x) {
    const unsigned o = (unsigned)__builtin_amdgcn_update_dpp((int)x, (int)x, CTRL, 0xf, 0xf, false);
    return o < x ? o : x;
}
__device__ __forceinline__ unsigned wave_min_u32(unsigned x) {
    x = dpp_min_step<0x111>(x);   // row_shr:1
    x = dpp_min_step<0x112>(x);   // row_shr:2
    x = dpp_min_step<0x114>(x);   // row_shr:4
    x = dpp_min_step<0x118>(x);   // row_shr:8
    x = dpp_min_step<0x142>(x);   // row_bcast:15
    x = dpp_min_step<0x143>(x);   // row_bcast:31
    return (unsigned)__builtin_amdgcn_readlane((int)x, 63);
}

__device__ __forceinline__ float readlane_f(float x, int lane_idx) {
    return __int_as_float(__builtin_amdgcn_readlane(__float_as_int(x), lane_idx));
}
__device__ __forceinline__ float sel4f(float a0, float a1, float a2, float a3, int s) {
    float r = a0;
    r = (s == 1) ? a1 : r;
    r = (s == 2) ? a2 : r;
    r = (s == 3) ? a3 : r;
    return r;
}
__device__ __forceinline__ int sel4i(int a0, int a1, int a2, int a3, int s) {
    int r = a0;
    r = (s == 1) ? a1 : r;
    r = (s == 2) ? a2 : r;
    r = (s == 3) ? a3 : r;
    return r;
}

// ---------------------------------------------------------------------------
// LSA, one wave per batch. Lane t owns rows AND cols 4t..4t+3.
// Stage 1: column reduction (v=colmin) + greedy tight matching + LDS staging.
// Stage 2: parallel Jacobi auction sweeps (eps=0), scans from GLOBAL (bank-
//   conflict-free); bids via LDS u64 atomicMax. Maintains dual feasibility +
//   tight matched edges (validated in R6).
// Stage 3: single-source SAP per remaining free row (exact JV phase, same
//   dual updates as reference) -> unique optimum == reference.
// ---------------------------------------------------------------------------
__global__ __launch_bounds__(64)
void lsa_kernel(const float* __restrict__ Cmat,
                float* __restrict__ out_row,
                float* __restrict__ out_col) {
    const int b = blockIdx.x;
    const int t = threadIdx.x;
    const int jb = 4 * t;
    const float* C = Cmat + (size_t)b * NROW * MCOL;

    __shared__ float Cc[CROWS][MCOL];               // 153600 B row cache
    __shared__ __align__(16) float v_lds[MCOL];     // col duals (live in stage 2)
    __shared__ unsigned long long bid_s[MCOL];      // bid keys; aliased argrow in CR
    __shared__ int r4c_s[MCOL];
    __shared__ int c4r_s[NROW];
    int* const argrow_s = (int*)bid_s;

    // ---------------- stage 1: column reduction + LDS staging ----------------
    float m0 = INF_F, m1 = INF_F, m2 = INF_F, m3 = INF_F;
    int   r0 = 0, r1 = 0, r2 = 0, r3 = 0;
    for (int i = 0; i < NROW; i++) {
        const float4 c4 = *(const float4*)(C + (size_t)i * MCOL + jb);
        if (i < CROWS) *(float4*)&Cc[i][jb] = c4;
        if (c4.x < m0) { m0 = c4.x; r0 = i; }
        if (c4.y < m1) { m1 = c4.y; r1 = i; }
        if (c4.z < m2) { m2 = c4.z; r2 = i; }
        if (c4.w < m3) { m3 = c4.w; r3 = i; }
    }
    float u0 = 0.f, u1 = 0.f, u2 = 0.f, u3 = 0.f;   // u[i], owner lane regs

    v_lds[jb + 0] = m0; v_lds[jb + 1] = m1;
    v_lds[jb + 2] = m2; v_lds[jb + 3] = m3;
    argrow_s[jb + 0] = r0; argrow_s[jb + 1] = r1;
    argrow_s[jb + 2] = r2; argrow_s[jb + 3] = r3;
    for (int k = 0; k < 4; k++) { c4r_s[jb + k] = -1; r4c_s[jb + k] = -1; }
    __syncthreads();

    if (t == 0) {   // greedy tight matching on column minima
        for (int j = 0; j < MCOL; j++) {
            const int r = argrow_s[j];
            if (c4r_s[r] < 0) { c4r_s[r] = j; r4c_s[j] = r; }
        }
    }
    __syncthreads();

    // ---------------- stage 2: parallel auction sweeps (global scans) --------
    for (int sweep = 0; sweep < MAXSWEEP; sweep++) {
        const int4 myc = *(const int4*)&c4r_s[jb];   // my rows' match state
        const unsigned long long f0 = __ballot(myc.x < 0);
        const unsigned long long f1 = __ballot(myc.y < 0);
        const unsigned long long f2 = __ballot(myc.z < 0);
        const unsigned long long f3 = __ballot(myc.w < 0);
        const int nfree = __popcll(f0) + __popcll(f1) + __popcll(f2) + __popcll(f3);
        if (nfree <= FREETHRESH) break;

        bid_s[jb + 0] = 0; bid_s[jb + 1] = 0;
        bid_s[jb + 2] = 0; bid_s[jb + 3] = 0;
        __syncthreads();

        const bool fr[4] = { myc.x < 0, myc.y < 0, myc.z < 0, myc.w < 0 };
        int bj[4]; float gap[4], mu2v[4]; unsigned long long key[4];

        #pragma unroll
        for (int s = 0; s < 4; s++) {
            bj[s] = -1; gap[s] = 0.f; mu2v[s] = 0.f; key[s] = 0;
            if (!fr[s]) continue;
            const int i = jb + s;
            const float* rowp = C + (size_t)i * MCOL;   // GLOBAL scan: no bank conflicts
            unsigned bk1 = 0xFFFFFFFFu, bk2 = 0xFFFFFFFFu; int bjj = 0;
            for (int j = 0; j < MCOL; j += 4) {
                const float4 vv = *(const float4*)&v_lds[j];   // broadcast read
                const float4 cc = *(const float4*)(rowp + j);
                unsigned k;
                k = ordkey(cc.x - vv.x); if (k < bk1) { bk2 = bk1; bk1 = k; bjj = j + 0; } else if (k < bk2) bk2 = k;
                k = ordkey(cc.y - vv.y); if (k < bk1) { bk2 = bk1; bk1 = k; bjj = j + 1; } else if (k < bk2) bk2 = k;
                k = ordkey(cc.z - vv.z); if (k < bk1) { bk2 = bk1; bk1 = k; bjj = j + 2; } else if (k < bk2) bk2 = k;
                k = ordkey(cc.w - vv.w); if (k < bk1) { bk2 = bk1; bk1 = k; bjj = j + 3; } else if (k < bk2) bk2 = k;
            }
            const float mu1 = unordkey(bk1), mu2 = unordkey(bk2);
            gap[s] = mu2 - mu1; mu2v[s] = mu2; bj[s] = bjj;
            key[s] = ((unsigned long long)ordkey(gap[s]) << 32) | (unsigned)i;
            atomicMax(&bid_s[bjj], key[s]);
        }
        __syncthreads();

        int kold[4];
        #pragma unroll
        for (int s = 0; s < 4; s++) {
            kold[s] = -2;   // -2 = not a winner
            if (bj[s] >= 0 && bid_s[bj[s]] == key[s]) kold[s] = r4c_s[bj[s]];
        }
        __syncthreads();

        #pragma unroll
        for (int s = 0; s < 4; s++) {
            if (kold[s] >= -1) {
                const int i = jb + s, j1 = bj[s];
                r4c_s[j1] = i;
                c4r_s[i] = j1;
                if (kold[s] >= 0) c4r_s[kold[s]] = -1;
                v_lds[j1] -= gap[s];
                if (s == 0) u0 = mu2v[0];
                else if (s == 1) u1 = mu2v[1];
                else if (s == 2) u2 = mu2v[2];
                else u3 = mu2v[3];
            }
        }
        __syncthreads();
    }

    // refresh register mirrors
    int4 q;
    q = *(const int4*)&r4c_s[jb];
    int rc0 = q.x, rc1 = q.y, rc2 = q.z, rc3 = q.w;
    q = *(const int4*)&c4r_s[jb];
    int cr0 = q.x, cr1 = q.y, cr2 = q.z, cr3 = q.w;
    const float4 vq = *(const float4*)&v_lds[jb];
    float v0 = vq.x, v1 = vq.y, v2 = vq.z, v3 = vq.w;

    // ---------------- stage 3: single-source SAP per free row (exact) --------
    unsigned long long mm0 = __ballot(cr0 < 0);
    unsigned long long mm1 = __ballot(cr1 < 0);
    unsigned long long mm2 = __ballot(cr2 < 0);
    unsigned long long mm3 = __ballot(cr3 < 0);

    while (mm0 | mm1 | mm2 | mm3) {
        int cur;
        if      (mm0) { const int l = __ffsll(mm0) - 1; mm0 &= mm0 - 1; cur = 4 * l + 0; }
        else if (mm1) { const int l = __ffsll(mm1) - 1; mm1 &= mm1 - 1; cur = 4 * l + 1; }
        else if (mm2) { const int l = __ffsll(mm2) - 1; mm2 &= mm2 - 1; cur = 4 * l + 2; }
        else          { const int l = __ffsll(mm3) - 1; mm3 &= mm3 - 1; cur = 4 * l + 3; }

        float s0 = INF_F, s1 = INF_F, s2 = INF_F, s3 = INF_F;  // spc
        int   p0 = -1,    p1 = -1,    p2 = -1,    p3 = -1;     // path
        float e0 = 0.f, e1 = 0.f, e2 = 0.f, e3 = 0.f;          // entering dist
        int scmask = 0, srmask = 0;
        int i = cur, sink = -1;
        float minVal = 0.f;

        for (int it = 0; it < MCOL; it++) {
            if ((i >> 2) == t) {            // mark scanned + record entering dist
                const int s = i & 3;
                srmask |= 1 << s;
                e0 = s == 0 ? minVal : e0; e1 = s == 1 ? minVal : e1;
                e2 = s == 2 ? minVal : e2; e3 = s == 3 ? minVal : e3;
            }
            const float ui = readlane_f(sel4f(u0, u1, u2, u3, i & 3), i >> 2);
            float4 c4;
            if (i < CROWS) c4 = *(const float4*)&Cc[i][jb];
            else           c4 = *(const float4*)(C + (size_t)i * MCOL + jb);
            const float base = minVal - ui;
            float d;
            d = base + c4.x - v0; if (!(scmask & 1) && d < s0) { s0 = d; p0 = i; }
            d = base + c4.y - v1; if (!(scmask & 2) && d < s1) { s1 = d; p1 = i; }
            d = base + c4.z - v2; if (!(scmask & 4) && d < s2) { s2 = d; p2 = i; }
            d = base + c4.w - v3; if (!(scmask & 8) && d < s3) { s3 = d; p3 = i; }

            unsigned lmin = 0xFFFFFFFFu; int lslot = 0, lrc = -1;
            if (!(scmask & 1)) { const unsigned k = ordkey(s0); if (k < lmin) { lmin = k; lslot = 0; lrc = rc0; } }
            if (!(scmask & 2)) { const unsigned k = ordkey(s1); if (k < lmin) { lmin = k; lslot = 1; lrc = rc1; } }
            if (!(scmask & 4)) { const unsigned k = ordkey(s2); if (k < lmin) { lmin = k; lslot = 2; lrc = rc2; } }
            if (!(scmask & 8)) { const unsigned k = ordkey(s3); if (k < lmin) { lmin = k; lslot = 3; lrc = rc3; } }

            const unsigned g = wave_min_u32(lmin);
            const unsigned long long bal = __ballot(lmin == g);
            const int w = __ffsll(bal) - 1;
            const int pk = __builtin_amdgcn_readlane(((lrc + 1) << 2) | lslot, w);
            const int mj = 4 * w + (pk & 3);
            const int rcx = (pk >> 2) - 1;
            minVal = unordkey(g);

            if (w == t) scmask |= 1 << (pk & 3);
            if (rcx < 0) { sink = mj; break; }
            i = rcx;
        }

        // dual updates (reference formulas; e_cur = 0 so cur gets +minVal)
        if (srmask & 1) u0 += minVal - e0;
        if (srmask & 2) u1 += minVal - e1;
        if (srmask & 4) u2 += minVal - e2;
        if (srmask & 8) u3 += minVal - e3;
        if (scmask & 1) v0 -= (minVal - s0);
        if (scmask & 2) v1 -= (minVal - s1);
        if (scmask & 4) v2 -= (minVal - s2);
        if (scmask & 8) v3 -= (minVal - s3);

        // augment along predecessor path (registers + readlane)
        int j = sink;
        for (int g2 = 0; g2 < NROW; g2++) {
            const int pi = __builtin_amdgcn_readlane(
                sel4i(p0, p1, p2, p3, j & 3), j >> 2);        // path[j]
            if ((j >> 2) == t) {                              // row4col[j] = pi
                const int s = j & 3;
                rc0 = s == 0 ? pi : rc0; rc1 = s == 1 ? pi : rc1;
                rc2 = s == 2 ? pi : rc2; rc3 = s == 3 ? pi : rc3;
            }
            const int jn = __builtin_amdgcn_readlane(
                sel4i(cr0, cr1, cr2, cr3, pi & 3), pi >> 2);  // old col4row[pi]
            if ((pi >> 2) == t) {                             // col4row[pi] = j
                const int s = pi & 3;
                cr0 = s == 0 ? j : cr0; cr1 = s == 1 ? j : cr1;
                cr2 = s == 2 ? j : cr2; cr3 = s == 3 ? j : cr3;
            }
            if (jn < 0) break;                                // reached free row (cur)
            j = jn;
        }
    }

    out_row[b * NROW + jb + 0] = (float)(jb + 0);
    out_row[b * NROW + jb + 1] = (float)(jb + 1);
    out_row[b * NROW + jb + 2] = (float)(jb + 2);
    out_row[b * NROW + jb + 3] = (float)(jb + 3);
    out_col[b * NROW + jb + 0] = (float)cr0;
    out_col[b * NROW + jb + 1] = (float)cr1;
    out_col[b * NROW + jb + 2] = (float)cr2;
    out_col[b * NROW + jb + 3] = (float)cr3;
}

// ---------------------------------------------------------------------------
extern "C" void kernel_launch(void* const* d_in, const int* in_sizes, int n_in,
                              void* d_out, int out_size, void* d_ws, size_t ws_size,
                              hipStream_t stream) {
    const float* pred_ctrl   = (const float*)d_in[0];
    const float* pred_logits = (const float*)d_in[1];
    const float* gt_ctrl     = (const float*)d_in[2];
    const int*   gt_labels   = (const int*)d_in[3];

    float* out     = (float*)d_out;
    float* out_row = out;
    float* out_col = out + BATCH * NROW;
    float* Cout    = out + 2 * BATCH * NROW;

    cost_fused_kernel<<<BATCH * NROW, 256, 0, stream>>>(pred_ctrl, pred_logits,
                                                        gt_ctrl, gt_labels, Cout);
    lsa_kernel<<<BATCH, 64, 0, stream>>>(Cout, out_row, out_col);
}